// Round 8
// baseline (175.915 us; speedup 1.0000x reference)
//
#include <hip/hip_runtime.h>

#define HDIM 20
#define BLOCK 64

typedef __fp16 half8 __attribute__((ext_vector_type(8)));
typedef __fp16 half2v __attribute__((ext_vector_type(2)));
typedef float  float4v __attribute__((ext_vector_type(4)));
typedef float  float2v __attribute__((ext_vector_type(2)));
typedef int    int4v  __attribute__((ext_vector_type(4)));

static __device__ __forceinline__ float4v mfma16(half8 a, half8 b, float4v c) {
    return __builtin_amdgcn_mfma_f32_16x16x32_f16(a, b, c, 0, 0, 0);
}

// KEY INVARIANT (no cross-lane traffic in the 200-step loop):
//   B-row permutation: k = 8q + i <-> hidden unit 4i + q (i<5; i=5,6 pad; k=7(q=0) bias=1).
//   C/D layout (m89): lane (q,el) holds D rows 4q..4q+3 of column el.
//   A tile T, row 4q'+g = unit 4T+q', gate g in {r,z,nI,nH} -> lane (q,el)
//   computes h_new for units {4T+q} = exactly its own B rows k=8q+T.
// Round 8: ONE wave carries TWO independent 16-element groups (A/B). Their
// serial chains interleave in-wave (ILP replaces the 2-wave TLP that left
// 35% idle); elementwise math in float2 -> v_pk_* packed fp32.
// A rows pre-scaled: r,z by -log2e ; nI,nH by +2log2e.

__global__ __launch_bounds__(BLOCK, 1) void gru_decoder_kernel(
    const float* __restrict__ hidden,
    const float* __restrict__ w_ih,
    const float* __restrict__ w_hh,
    const float* __restrict__ b_ih,
    const float* __restrict__ b_hh,
    const float* __restrict__ w_l,
    const float* __restrict__ b_l,
    const int*  __restrict__ step_ptr,
    float* __restrict__ out,
    int B)
{
    const int l   = threadIdx.x & 63;
    const int el  = l & 15;
    const int q   = l >> 4;
    const int eA  = blockIdx.x * 32 + el;     // group A element
    const int eB  = eA + 16;                  // group B element
    const int step = *step_ptr;

    const float NL2E  = -1.4426950408889634f;
    const float T2L2E =  2.8853900817779268f;

    // ---- A fragments (shared by both groups) ----
    const int u_dst = el >> 2;
    const int g     = el & 3;

    half8 Afold[5], Azero[5], Ay;
    #pragma unroll
    for (int T = 0; T < 5; ++T) {
        const int u  = 4 * T + u_dst;
        const int rr = (g == 0) ? u : (g == 1) ? 20 + u : 40 + u;
        const float sc = (g <= 1) ? NL2E : T2L2E;
        half8 hf, h0;
        #pragma unroll
        for (int j = 0; j < 8; ++j) {
            float af = 0.f, a0 = 0.f;
            if (j < 5) {
                const int uk = 4 * j + q;
                float wx = w_ih[rr * 2 + 0] * w_l[uk] + w_ih[rr * 2 + 1] * w_l[HDIM + uk];
                float wh = w_hh[rr * HDIM + uk];
                if (g <= 1)      { af = wh + wx; a0 = wh; }
                else if (g == 2) { af = wx;      a0 = 0.f; }
                else             { af = wh;      a0 = wh; }
            } else if (j == 7 && q == 0) {
                float bx = w_ih[rr * 2 + 0] * b_l[0] + w_ih[rr * 2 + 1] * b_l[1];
                if (g <= 1)      { af = b_ih[rr] + b_hh[rr] + bx; a0 = b_ih[rr] + b_hh[rr]; }
                else if (g == 2) { af = b_ih[rr] + bx;            a0 = b_ih[rr]; }
                else             { af = b_hh[rr];                 a0 = b_hh[rr]; }
            }
            hf[j] = (__fp16)(af * sc);
            h0[j] = (__fp16)(a0 * sc);
        }
        Afold[T] = hf;
        Azero[T] = h0;
    }
    {
        half8 hy;
        #pragma unroll
        for (int j = 0; j < 8; ++j) {
            float v = 0.f;
            if (el < 2) {
                if (j < 5)                 v = w_l[el * HDIM + 4 * j + q];
                else if (j == 7 && q == 0) v = b_l[el];
            }
            hy[j] = (__fp16)v;
        }
        Ay = hy;
    }

    int w3const;
    {
        half2v c67; c67[0] = (__fp16)0.f; c67[1] = (__fp16)((q == 0) ? 1.f : 0.f);
        w3const = __builtin_bit_cast(int, c67);
    }

    // ---- state: hp[T] = (h_A, h_B) ----
    float2v hp[5];
    half8 BfA, BfB;
    {
        const float* ha = hidden + (size_t)eA * HDIM;
        const float* hb = hidden + (size_t)eB * HDIM;
        #pragma unroll
        for (int T = 0; T < 5; ++T) {
            hp[T][0] = ha[4 * T + q];
            hp[T][1] = hb[4 * T + q];
        }
        int4v ba, bb;
        ba[0] = __builtin_bit_cast(int, __builtin_amdgcn_cvt_pkrtz(hp[0][0], hp[1][0]));
        ba[1] = __builtin_bit_cast(int, __builtin_amdgcn_cvt_pkrtz(hp[2][0], hp[3][0]));
        ba[2] = __builtin_bit_cast(int, __builtin_amdgcn_cvt_pkrtz(hp[4][0], 0.f));
        ba[3] = w3const;
        bb[0] = __builtin_bit_cast(int, __builtin_amdgcn_cvt_pkrtz(hp[0][1], hp[1][1]));
        bb[1] = __builtin_bit_cast(int, __builtin_amdgcn_cvt_pkrtz(hp[2][1], hp[3][1]));
        bb[2] = __builtin_bit_cast(int, __builtin_amdgcn_cvt_pkrtz(hp[4][1], 0.f));
        bb[3] = w3const;
        BfA = __builtin_bit_cast(half8, ba);
        BfB = __builtin_bit_cast(half8, bb);
    }

    const float4v czero = {0.f, 0.f, 0.f, 0.f};

    auto do_step = [&](const half8* A) {
        float4v CA[5], CB[5];
        #pragma unroll
        for (int T = 0; T < 5; ++T) {
            CA[T] = mfma16(A[T], BfA, czero);
            CB[T] = mfma16(A[T], BfB, czero);
        }
        #pragma unroll
        for (int T = 0; T < 5; ++T) {
            float2v c0; c0[0] = CA[T][0]; c0[1] = CB[T][0];
            float2v c1; c1[0] = CA[T][1]; c1[1] = CB[T][1];
            float2v c2; c2[0] = CA[T][2]; c2[1] = CB[T][2];
            float2v c3; c3[0] = CA[T][3]; c3[1] = CB[T][3];
            float2v e0, e1;
            e0[0] = __builtin_amdgcn_exp2f(c0[0]); e0[1] = __builtin_amdgcn_exp2f(c0[1]);
            e1[0] = __builtin_amdgcn_exp2f(c1[0]); e1[1] = __builtin_amdgcn_exp2f(c1[1]);
            float2v a0 = e0 + 1.f;
            float2v a1 = e1 + 1.f;
            float2v r, z;
            r[0] = __builtin_amdgcn_rcpf(a0[0]); r[1] = __builtin_amdgcn_rcpf(a0[1]);
            z[0] = __builtin_amdgcn_rcpf(a1[0]); z[1] = __builtin_amdgcn_rcpf(a1[1]);
            float2v np = c2 + r * c3;
            float2v e2;
            e2[0] = __builtin_amdgcn_exp2f(np[0]); e2[1] = __builtin_amdgcn_exp2f(np[1]);
            float2v a2 = e2 + 1.f;
            float2v tn;
            tn[0] = __builtin_amdgcn_rcpf(a2[0]); tn[1] = __builtin_amdgcn_rcpf(a2[1]);
            float2v n = 1.f - 2.f * tn;
            hp[T] = n + z * (hp[T] - n);       // (1-z)*n + z*h, packed
        }
        int4v ba, bb;
        ba[0] = __builtin_bit_cast(int, __builtin_amdgcn_cvt_pkrtz(hp[0][0], hp[1][0]));
        ba[1] = __builtin_bit_cast(int, __builtin_amdgcn_cvt_pkrtz(hp[2][0], hp[3][0]));
        ba[2] = __builtin_bit_cast(int, __builtin_amdgcn_cvt_pkrtz(hp[4][0], 0.f));
        ba[3] = w3const;
        bb[0] = __builtin_bit_cast(int, __builtin_amdgcn_cvt_pkrtz(hp[0][1], hp[1][1]));
        bb[1] = __builtin_bit_cast(int, __builtin_amdgcn_cvt_pkrtz(hp[2][1], hp[3][1]));
        bb[2] = __builtin_bit_cast(int, __builtin_amdgcn_cvt_pkrtz(hp[4][1], 0.f));
        bb[3] = w3const;
        BfA = __builtin_bit_cast(half8, ba);
        BfB = __builtin_bit_cast(half8, bb);
    };

    float* outA = out + (size_t)eA * 2 * step;
    float* outB = out + (size_t)eB * 2 * step;

    do_step(Azero);                                   // h_0 -> h_1 (x=0 step)
    for (int t = 1; t < step; ++t) {
        float4v cyA = mfma16(Ay, BfA, czero);         // y_{t-1}
        float4v cyB = mfma16(Ay, BfB, czero);
        if (q == 0) {
            float2 sa; sa.x = cyA[0]; sa.y = cyA[1];
            float2 sb; sb.x = cyB[0]; sb.y = cyB[1];
            *(float2*)(outA + 2 * (step - t)) = sa;   // reversed time index
            *(float2*)(outB + 2 * (step - t)) = sb;
        }
        do_step(Afold);                               // h_t -> h_{t+1}
    }
    {
        float4v cyA = mfma16(Ay, BfA, czero);
        float4v cyB = mfma16(Ay, BfB, czero);
        if (q == 0) {
            float2 sa; sa.x = cyA[0]; sa.y = cyA[1];
            float2 sb; sb.x = cyB[0]; sb.y = cyB[1];
            *(float2*)(outA + 0) = sa;
            *(float2*)(outB + 0) = sb;
        }
    }
}

extern "C" void kernel_launch(void* const* d_in, const int* in_sizes, int n_in,
                              void* d_out, int out_size, void* d_ws, size_t ws_size,
                              hipStream_t stream) {
    const float* hidden = (const float*)d_in[0];
    const float* w_ih   = (const float*)d_in[1];
    const float* w_hh   = (const float*)d_in[2];
    const float* b_ih   = (const float*)d_in[3];
    const float* b_hh   = (const float*)d_in[4];
    const float* w_l    = (const float*)d_in[5];
    const float* b_l    = (const float*)d_in[6];
    const int*   step   = (const int*)d_in[7];
    float* out = (float*)d_out;

    int B = in_sizes[0] / HDIM;     // hidden is (1, B, 20); B = 32768
    int grid = B / 32;              // 1 wave per block, 2x16 elements per wave

    gru_decoder_kernel<<<grid, BLOCK, 0, stream>>>(
        hidden, w_ih, w_hh, b_ih, b_hh, w_l, b_l, step, out, B);
}